// Round 1
// baseline (1776.822 us; speedup 1.0000x reference)
//
#include <hip/hip_runtime.h>
#include <math.h>

#define BB 8
#define CC 256
#define HH 64
#define WWIDTH 64
#define PLANE 4096      // 64*64
#define IMG   1048576   // 256*4096
#define EPS 1e-5f

// ---------------- weight prep: transpose to [ci][tap][co] ----------------
__global__ void k_prep(const float* __restrict__ w1, const float* __restrict__ wd,
                       const float* __restrict__ woff, const float* __restrict__ wmod,
                       const float* __restrict__ wds,
                       float* __restrict__ wt1, float* __restrict__ wtd,
                       float* __restrict__ wtom, float* __restrict__ wtds) {
  int stride = gridDim.x * blockDim.x;
  int tid0 = blockIdx.x * blockDim.x + threadIdx.x;
  for (int s = tid0; s < 256 * 9 * 256; s += stride) {
    int co = s & 255; int t = s >> 8; int tap = t % 9; int ci = t / 9;
    wt1[s] = w1[(co * 256 + ci) * 9 + tap];
    wtd[s] = wd[(co * 256 + ci) * 9 + tap];
  }
  for (int s = tid0; s < 256 * 9 * 28; s += stride) {
    int co = s % 28; int t = s / 28; int tap = t % 9; int ci = t / 9;
    float v = 0.f;
    if (co < 18) v = woff[(co * 256 + ci) * 9 + tap];
    else if (co < 27) v = wmod[((co - 18) * 256 + ci) * 9 + tap];
    wtom[s] = v;
  }
  for (int s = tid0; s < 256 * 256; s += stride) {
    int co = s & 255; int ci = s >> 8;
    wtds[s] = wds[co * 256 + ci];
  }
}

// ---------------- conv 3x3, 256->256, pad 1 (direct, tiled) ----------------
// grid (4, 64, 8) = (co_tile, h, b); 256 threads; thread computes 4co x 4pix
__global__ __launch_bounds__(256) void k_conv3(const float* __restrict__ x,
                                               const float* __restrict__ wt,
                                               const float* __restrict__ bias,
                                               float* __restrict__ out) {
  __shared__ __align__(16) float sIn[8][3][72];
  __shared__ __align__(16) float sW[8][9][64];
  const int co0 = blockIdx.x * 64, h = blockIdx.y, b = blockIdx.z;
  const int tid = threadIdx.x;
  const int pix = (tid & 15) * 4;
  const int cog = tid >> 4;
  float acc[4][4] = {};
  const float* xb = x + b * IMG;
  for (int cchunk = 0; cchunk < 32; ++cchunk) {
    const int ci0 = cchunk * 8;
    for (int s = tid; s < 8 * 3 * 66; s += 256) {
      int xcol = s % 66; int t = s / 66; int ky = t % 3; int ci = t / 3;
      int gy = h + ky - 1, gx = xcol - 1;
      float v = 0.f;
      if ((unsigned)gy < 64u && (unsigned)gx < 64u) v = xb[(ci0 + ci) * PLANE + gy * 64 + gx];
      sIn[ci][ky][xcol] = v;
    }
    for (int s = tid; s < 8 * 9 * 64; s += 256) {
      int co = s & 63; int t = s >> 6; int tap = t % 9; int ci = t / 9;
      sW[ci][tap][co] = wt[((ci0 + ci) * 9 + tap) * 256 + co0 + co];
    }
    __syncthreads();
    #pragma unroll
    for (int ci = 0; ci < 8; ++ci) {
      #pragma unroll
      for (int ky = 0; ky < 3; ++ky) {
        float r[6];
        float4 rv = *(const float4*)&sIn[ci][ky][pix];
        r[0] = rv.x; r[1] = rv.y; r[2] = rv.z; r[3] = rv.w;
        r[4] = sIn[ci][ky][pix + 4];
        r[5] = sIn[ci][ky][pix + 5];
        #pragma unroll
        for (int kx = 0; kx < 3; ++kx) {
          float4 wv = *(const float4*)&sW[ci][ky * 3 + kx][cog * 4];
          float w[4] = {wv.x, wv.y, wv.z, wv.w};
          #pragma unroll
          for (int i = 0; i < 4; ++i)
            #pragma unroll
            for (int j = 0; j < 4; ++j)
              acc[i][j] += w[i] * r[j + kx];
        }
      }
    }
    __syncthreads();
  }
  #pragma unroll
  for (int i = 0; i < 4; ++i) {
    int co = co0 + cog * 4 + i;
    float bv = bias[co];
    float4 o = {acc[i][0] + bv, acc[i][1] + bv, acc[i][2] + bv, acc[i][3] + bv};
    *(float4*)&out[b * IMG + co * PLANE + h * 64 + pix] = o;
  }
}

// ---------------- BN stats: one block per channel -> scale/shift ----------------
__global__ __launch_bounds__(256) void k_bnstats(const float* __restrict__ t,
                                                 const float* __restrict__ g,
                                                 const float* __restrict__ bt,
                                                 float* __restrict__ scale,
                                                 float* __restrict__ shift) {
  const int c = blockIdx.x, tid = threadIdx.x;
  float s1 = 0.f, s2 = 0.f;
  for (int b = 0; b < BB; ++b) {
    const float4* p = (const float4*)(t + b * IMG + c * PLANE);
    for (int i = tid; i < PLANE / 4; i += 256) {
      float4 v = p[i];
      s1 += v.x + v.y + v.z + v.w;
      s2 += v.x * v.x + v.y * v.y + v.z * v.z + v.w * v.w;
    }
  }
  #pragma unroll
  for (int o = 32; o > 0; o >>= 1) { s1 += __shfl_down(s1, o); s2 += __shfl_down(s2, o); }
  __shared__ float a1[4], a2[4];
  if ((tid & 63) == 0) { a1[tid >> 6] = s1; a2[tid >> 6] = s2; }
  __syncthreads();
  if (tid == 0) {
    float S1 = a1[0] + a1[1] + a1[2] + a1[3];
    float S2 = a2[0] + a2[1] + a2[2] + a2[3];
    const float inv = 1.f / (float)(BB * PLANE);
    float m = S1 * inv;
    float var = S2 * inv - m * m;
    float a = g[c] * rsqrtf(var + EPS);
    scale[c] = a;
    shift[c] = bt[c] - m * a;
  }
}

// ---------------- apply BN + relu ----------------
__global__ void k_bnrelu(const float* __restrict__ t, const float* __restrict__ scale,
                         const float* __restrict__ shift, float* __restrict__ o) {
  int stride = gridDim.x * blockDim.x;
  for (int i = blockIdx.x * blockDim.x + threadIdx.x; i < (BB * IMG) / 4; i += stride) {
    float4 v = ((const float4*)t)[i];
    int c = (i >> 10) & 255;
    float a = scale[c], sh = shift[c];
    float4 r;
    r.x = fmaxf(v.x * a + sh, 0.f);
    r.y = fmaxf(v.y * a + sh, 0.f);
    r.z = fmaxf(v.z * a + sh, 0.f);
    r.w = fmaxf(v.w * a + sh, 0.f);
    ((float4*)o)[i] = r;
  }
}

// ---------------- offset (18ch) + mask (9ch) conv 3x3 ----------------
// grid (64, 8) = (h, b); 256 threads; thread: 7 channels x 1 pixel
__global__ __launch_bounds__(256) void k_offmask(const float* __restrict__ in,
                                                 const float* __restrict__ wtom,
                                                 const float* __restrict__ boff,
                                                 const float* __restrict__ bmod,
                                                 float* __restrict__ offs,
                                                 float* __restrict__ mask) {
  __shared__ __align__(16) float sIn[8][3][72];
  __shared__ __align__(16) float sW[8][9][28];
  const int h = blockIdx.x, b = blockIdx.y, tid = threadIdx.x;
  const int px = tid & 63;
  const int cog = tid >> 6;  // 0..3 -> channels cog*7 .. cog*7+6 (28 rows incl pad)
  float acc[7] = {};
  const float* xb = in + b * IMG;
  for (int cchunk = 0; cchunk < 32; ++cchunk) {
    const int ci0 = cchunk * 8;
    for (int s = tid; s < 8 * 3 * 66; s += 256) {
      int xcol = s % 66; int t = s / 66; int ky = t % 3; int ci = t / 3;
      int gy = h + ky - 1, gx = xcol - 1;
      float v = 0.f;
      if ((unsigned)gy < 64u && (unsigned)gx < 64u) v = xb[(ci0 + ci) * PLANE + gy * 64 + gx];
      sIn[ci][ky][xcol] = v;
    }
    for (int s = tid; s < 8 * 9 * 28; s += 256)
      ((float*)sW)[s] = wtom[ci0 * 9 * 28 + s];
    __syncthreads();
    #pragma unroll
    for (int ci = 0; ci < 8; ++ci) {
      #pragma unroll
      for (int ky = 0; ky < 3; ++ky) {
        float r0 = sIn[ci][ky][px], r1 = sIn[ci][ky][px + 1], r2 = sIn[ci][ky][px + 2];
        #pragma unroll
        for (int kx = 0; kx < 3; ++kx) {
          float rv = (kx == 0) ? r0 : ((kx == 1) ? r1 : r2);
          #pragma unroll
          for (int i = 0; i < 7; ++i)
            acc[i] += sW[ci][ky * 3 + kx][cog * 7 + i] * rv;
        }
      }
    }
    __syncthreads();
  }
  #pragma unroll
  for (int i = 0; i < 7; ++i) {
    int c = cog * 7 + i;
    if (c < 18) {
      offs[(b * 18 + c) * PLANE + h * 64 + px] = acc[i] + boff[c];
    } else if (c < 27) {
      float m = acc[i] + bmod[c - 18];
      mask[(b * 9 + (c - 18)) * PLANE + h * 64 + px] = 2.f / (1.f + expf(-m));
    }
  }
}

// ---------------- modulated deformable conv ----------------
// grid (64, 8) = (h, b); 256 threads; full CO=256 per block; thread: 16co x 4pix
__global__ __launch_bounds__(256) void k_deform(const float* __restrict__ in,
                                                const float* __restrict__ offs,
                                                const float* __restrict__ mask,
                                                const float* __restrict__ wtd,
                                                const float* __restrict__ bd,
                                                float* __restrict__ out) {
  __shared__ __align__(16) float4 sSpecW[9][64];
  __shared__ int sY0[9][64];
  __shared__ int sX0[9][64];
  __shared__ __align__(16) float sWd[4][9][256];
  __shared__ __align__(16) float sSamp[4][9][68];
  const int h = blockIdx.x, b = blockIdx.y, tid = threadIdx.x;
  const int pixg = tid & 15;   // *4 pixels
  const int cog = tid >> 4;    // 0..15 -> co = cog*16 + i
  // phase 1: per-(tap,pixel) bilinear specs, computed once per block
  for (int s = tid; s < 576; s += 256) {
    int px = s & 63, p = s >> 6;
    float dy = offs[(b * 18 + 2 * p) * PLANE + h * 64 + px];
    float dx = offs[(b * 18 + 2 * p + 1) * PLANE + h * 64 + px];
    float mk = mask[(b * 9 + p) * PLANE + h * 64 + px];
    float py = (float)(h + p / 3 - 1) + dy;
    float pxx = (float)(px + p % 3 - 1) + dx;
    float fy = floorf(py), fx = floorf(pxx);
    float ly = py - fy, lx = pxx - fx;
    int y0 = (int)fy, x0 = (int)fx;
    bool vy0 = (y0 >= 0) && (y0 < 64);
    bool vy1 = (y0 + 1 >= 0) && (y0 + 1 < 64);
    bool vx0 = (x0 >= 0) && (x0 < 64);
    bool vx1 = (x0 + 1 >= 0) && (x0 + 1 < 64);
    float4 wv;
    wv.x = (1.f - ly) * (1.f - lx) * mk * ((vy0 && vx0) ? 1.f : 0.f);
    wv.y = (1.f - ly) * lx * mk * ((vy0 && vx1) ? 1.f : 0.f);
    wv.z = ly * (1.f - lx) * mk * ((vy1 && vx0) ? 1.f : 0.f);
    wv.w = ly * lx * mk * ((vy1 && vx1) ? 1.f : 0.f);
    sSpecW[p][px] = wv;
    sY0[p][px] = y0;
    sX0[p][px] = x0;
  }
  __syncthreads();
  float acc[16][4] = {};
  const float* xb = in + b * IMG;
  for (int cchunk = 0; cchunk < 64; ++cchunk) {
    const int ci0 = cchunk * 4;
    for (int s = tid; s < 4 * 9 * 256; s += 256)
      ((float*)sWd)[s] = wtd[ci0 * 9 * 256 + s];
    for (int s = tid; s < 4 * 9 * 64; s += 256) {
      int px = s & 63, t = s >> 6, p = t % 9, ci = t / 9;
      int y0 = sY0[p][px], x0 = sX0[p][px];
      float4 wv = sSpecW[p][px];
      const float* P = xb + (ci0 + ci) * PLANE;
      int iy0 = min(max(y0, 0), 63), iy1 = min(max(y0 + 1, 0), 63);
      int ix0 = min(max(x0, 0), 63), ix1 = min(max(x0 + 1, 0), 63);
      float v = wv.x * P[iy0 * 64 + ix0] + wv.y * P[iy0 * 64 + ix1]
              + wv.z * P[iy1 * 64 + ix0] + wv.w * P[iy1 * 64 + ix1];
      sSamp[ci][p][px] = v;
    }
    __syncthreads();
    #pragma unroll 1
    for (int p = 0; p < 9; ++p) {
      #pragma unroll
      for (int ci = 0; ci < 4; ++ci) {
        float4 rv = *(const float4*)&sSamp[ci][p][pixg * 4];
        float r[4] = {rv.x, rv.y, rv.z, rv.w};
        #pragma unroll
        for (int i4 = 0; i4 < 4; ++i4) {
          float4 wv = *(const float4*)&sWd[ci][p][cog * 16 + i4 * 4];
          float w[4] = {wv.x, wv.y, wv.z, wv.w};
          #pragma unroll
          for (int ii = 0; ii < 4; ++ii)
            #pragma unroll
            for (int j = 0; j < 4; ++j)
              acc[i4 * 4 + ii][j] += w[ii] * r[j];
        }
      }
    }
    __syncthreads();
  }
  #pragma unroll
  for (int i = 0; i < 16; ++i) {
    int co = cog * 16 + i;
    float bv = bd[co];
    float4 o = {acc[i][0] + bv, acc[i][1] + bv, acc[i][2] + bv, acc[i][3] + bv};
    *(float4*)&out[b * IMG + co * PLANE + h * 64 + pixg * 4] = o;
  }
}

// ---------------- 1x1 conv residual ----------------
// grid (4, 64, 8) = (co_tile, h, b); thread: 4co x 4pix
__global__ __launch_bounds__(256) void k_res(const float* __restrict__ x,
                                             const float* __restrict__ wtds,
                                             const float* __restrict__ bds,
                                             float* __restrict__ out) {
  __shared__ __align__(16) float sX[32][64];
  __shared__ __align__(16) float sW[32][64];
  const int co0 = blockIdx.x * 64, h = blockIdx.y, b = blockIdx.z;
  const int tid = threadIdx.x;
  const int pix = (tid & 15) * 4;
  const int cog = tid >> 4;
  float acc[4][4] = {};
  for (int cchunk = 0; cchunk < 8; ++cchunk) {
    const int ci0 = cchunk * 32;
    for (int s = tid; s < 2048; s += 256) {
      int p = s & 63, ci = s >> 6;
      sX[ci][p] = x[b * IMG + (ci0 + ci) * PLANE + h * 64 + p];
      sW[ci][p] = wtds[(ci0 + ci) * 256 + co0 + p];
    }
    __syncthreads();
    #pragma unroll
    for (int ci = 0; ci < 32; ++ci) {
      float4 xv = *(const float4*)&sX[ci][pix];
      float4 wv = *(const float4*)&sW[ci][cog * 4];
      float r[4] = {xv.x, xv.y, xv.z, xv.w};
      float w[4] = {wv.x, wv.y, wv.z, wv.w};
      #pragma unroll
      for (int i = 0; i < 4; ++i)
        #pragma unroll
        for (int j = 0; j < 4; ++j)
          acc[i][j] += w[i] * r[j];
    }
    __syncthreads();
  }
  #pragma unroll
  for (int i = 0; i < 4; ++i) {
    int co = co0 + cog * 4 + i;
    float bv = bds[co];
    float4 o = {acc[i][0] + bv, acc[i][1] + bv, acc[i][2] + bv, acc[i][3] + bv};
    *(float4*)&out[b * IMG + co * PLANE + h * 64 + pix] = o;
  }
}

// ---------------- final: relu(bn2(t2) + bn3(res)) ----------------
// sc points at [s2 | sh2 | s3 | sh3] (256 each). res aliases o (d_out): read-then-write same idx.
__global__ void k_final(const float* __restrict__ t2, const float* __restrict__ res,
                        const float* __restrict__ sc, float* __restrict__ o) {
  int stride = gridDim.x * blockDim.x;
  for (int i = blockIdx.x * blockDim.x + threadIdx.x; i < (BB * IMG) / 4; i += stride) {
    float4 a = ((const float4*)t2)[i];
    float4 r = ((const float4*)res)[i];
    int c = (i >> 10) & 255;
    float s2v = sc[c], sh2v = sc[256 + c], s3v = sc[512 + c], sh3v = sc[768 + c];
    float4 q;
    q.x = fmaxf(a.x * s2v + sh2v + r.x * s3v + sh3v, 0.f);
    q.y = fmaxf(a.y * s2v + sh2v + r.y * s3v + sh3v, 0.f);
    q.z = fmaxf(a.z * s2v + sh2v + r.z * s3v + sh3v, 0.f);
    q.w = fmaxf(a.w * s2v + sh2v + r.w * s3v + sh3v, 0.f);
    ((float4*)o)[i] = q;
  }
}

extern "C" void kernel_launch(void* const* d_in, const int* in_sizes, int n_in,
                              void* d_out, int out_size, void* d_ws, size_t ws_size,
                              hipStream_t stream) {
  const float* x    = (const float*)d_in[0];
  const float* w1   = (const float*)d_in[2];
  const float* b1   = (const float*)d_in[3];
  const float* g1   = (const float*)d_in[4];
  const float* bt1  = (const float*)d_in[5];
  const float* woff = (const float*)d_in[6];
  const float* boff = (const float*)d_in[7];
  const float* wmod = (const float*)d_in[8];
  const float* bmod = (const float*)d_in[9];
  const float* wd   = (const float*)d_in[10];
  const float* bd   = (const float*)d_in[11];
  const float* g2   = (const float*)d_in[12];
  const float* bt2  = (const float*)d_in[13];
  const float* wds  = (const float*)d_in[14];
  const float* bds  = (const float*)d_in[15];
  const float* g3   = (const float*)d_in[16];
  const float* bt3  = (const float*)d_in[17];

  float* ws   = (float*)d_ws;
  float* wt1  = ws;                    // 589824
  float* wtd  = wt1 + 589824;          // 589824
  float* wtom = wtd + 589824;          // 64512
  float* wtds = wtom + 64512;          // 65536
  float* SC   = wtds + 65536;          // 2048 (6*256 used)
  float* t1   = SC + 2048;             // 8388608
  float* out1 = t1 + 8388608;          // 8388608
  float* offs = out1 + 8388608;        // 589824
  float* mk   = offs + 589824;         // 294912
  float* t2   = mk + 294912;           // 8388608  (total ~109.5 MB of ws)
  float* res  = (float*)d_out;         // residual path lives in d_out

  k_prep<<<2048, 256, 0, stream>>>(w1, wd, woff, wmod, wds, wt1, wtd, wtom, wtds);
  k_conv3<<<dim3(4, 64, 8), 256, 0, stream>>>(x, wt1, b1, t1);
  k_bnstats<<<256, 256, 0, stream>>>(t1, g1, bt1, SC, SC + 256);
  k_bnrelu<<<2048, 256, 0, stream>>>(t1, SC, SC + 256, out1);
  k_offmask<<<dim3(64, 8), 256, 0, stream>>>(out1, wtom, boff, bmod, offs, mk);
  k_deform<<<dim3(64, 8), 256, 0, stream>>>(out1, offs, mk, wtd, bd, t2);
  k_bnstats<<<256, 256, 0, stream>>>(t2, g2, bt2, SC + 512, SC + 768);
  k_res<<<dim3(4, 64, 8), 256, 0, stream>>>(x, wtds, bds, res);
  k_bnstats<<<256, 256, 0, stream>>>(res, g3, bt3, SC + 1024, SC + 1280);
  k_final<<<2048, 256, 0, stream>>>(t2, res, SC + 512, (float*)d_out);
}

// Round 3
// 525.620 us; speedup vs baseline: 3.3804x; 3.3804x over previous
//
#include <hip/hip_runtime.h>
#include <math.h>

typedef __attribute__((ext_vector_type(8))) __bf16 bf16x8;
typedef __attribute__((ext_vector_type(4))) float f32x4;

#define PLANE 4096
#define IMG   1048576

__device__ inline ushort f2bf(float f) {
  uint u = __float_as_uint(f);
  u = (u + 0x7fffu + ((u >> 16) & 1u)) >> 16;
  return (ushort)u;
}

union frag_cv { uint4 u; bf16x8 v; };

// ---------------- weight prep: fp32 [co][ci][3][3] -> bf16 [p][cic][co][kk] ----------------
__global__ void k_prep(const float* __restrict__ w1, const float* __restrict__ wd,
                       const float* __restrict__ woff, const float* __restrict__ wmod,
                       const float* __restrict__ wds,
                       ushort* __restrict__ wb1, ushort* __restrict__ wbd,
                       ushort* __restrict__ wbom, ushort* __restrict__ wbds) {
  int stride = gridDim.x * blockDim.x;
  int t0 = blockIdx.x * blockDim.x + threadIdx.x;
  for (int s = t0; s < 9 * 8 * 256 * 32; s += stride) {
    int kk = s & 31, co = (s >> 5) & 255, cic = (s >> 13) & 7, p = s >> 16;
    int ci = cic * 32 + kk;
    wb1[s] = f2bf(w1[(co * 256 + ci) * 9 + p]);
    wbd[s] = f2bf(wd[(co * 256 + ci) * 9 + p]);
  }
  for (int s = t0; s < 9 * 8 * 32 * 32; s += stride) {
    int kk = s & 31, co = (s >> 5) & 31, cic = (s >> 10) & 7, p = s >> 13;
    int ci = cic * 32 + kk;
    float v = 0.f;
    if (co < 18) v = woff[(co * 256 + ci) * 9 + p];
    else if (co < 27) v = wmod[((co - 18) * 256 + ci) * 9 + p];
    wbom[s] = f2bf(v);
  }
  for (int s = t0; s < 8 * 256 * 32; s += stride) {
    int kk = s & 31, co = (s >> 5) & 255, cic = s >> 13;
    wbds[s] = f2bf(wds[co * 256 + cic * 32 + kk]);
  }
}

// ---------------- x NCHW fp32 -> xn NHWC bf16 ----------------
__global__ __launch_bounds__(256) void k_x2nhwc(const float* __restrict__ x,
                                                ushort* __restrict__ xn) {
  __shared__ __align__(16) float sT[64 * 68];
  const int h = blockIdx.x, b = blockIdx.y, t = threadIdx.x;
  for (int chunk = 0; chunk < 4; ++chunk) {
    const int c0 = chunk * 64;
    {
      int w4 = (t & 15) * 4, cl = t >> 4;
      #pragma unroll
      for (int i = 0; i < 4; ++i) {
        int c = cl * 4 + i;
        float4 v = *(const float4*)&x[((b * 256 + c0 + c) * 64 + h) * 64 + w4];
        *(float4*)&sT[c * 68 + w4] = v;
      }
    }
    __syncthreads();
    {
      int w = t & 63, cg = t >> 6;
      #pragma unroll
      for (int i = 0; i < 2; ++i) {
        int cg2 = cg * 2 + i;
        uint ou[4];
        #pragma unroll
        for (int k2 = 0; k2 < 4; ++k2) {
          float lo = sT[(cg2 * 8 + k2 * 2) * 68 + w];
          float hi = sT[(cg2 * 8 + k2 * 2 + 1) * 68 + w];
          ou[k2] = (uint)f2bf(lo) | ((uint)f2bf(hi) << 16);
        }
        *(uint4*)&xn[(((b * 64 + h) * 64 + w) * 256) + c0 + cg2 * 8] = *(uint4*)ou;
      }
    }
    __syncthreads();
  }
}

// ---------------- implicit-GEMM conv (3x3 pad1 or 1x1), bf16 MFMA ----------------
// grid (64, 8) = (h, b); 256 thr = 4 waves.
// NCO=256: wave owns 64 co, all 64 px (MF=4,NF=4). NCO=32: wave owns 16 px, 32 co.
// MODE 0: plain fp32 NHWC store. MODE 1: +bias, sigmoid on cols 18..26, store [row][32].
template<int NCO, int NTAP, int MODE>
__global__ __launch_bounds__(256) void k_conv(const ushort* __restrict__ an,
                                              const ushort* __restrict__ wB,
                                              const float* __restrict__ boff,
                                              const float* __restrict__ bmod,
                                              float* __restrict__ out) {
  __shared__ __align__(16) ushort sA[64 * 264];
  __shared__ __align__(16) ushort sB[NCO * 40];
  const int h = blockIdx.x, b = blockIdx.y, t = threadIdx.x;
  const int lane = t & 63, wv = t >> 6;
  constexpr int MF = (NCO == 256) ? 4 : 1;
  constexpr int NF = (NCO == 256) ? 4 : 2;
  const int co_w = (NCO == 256) ? wv * 64 : 0;
  const int m0 = (NCO == 256) ? 0 : wv;
  f32x4 acc[MF][NF];
  #pragma unroll
  for (int m = 0; m < MF; ++m)
    #pragma unroll
    for (int n = 0; n < NF; ++n) acc[m][n] = (f32x4){0.f, 0.f, 0.f, 0.f};

  const int spx = t & 63, seg = t >> 6;
  for (int p = 0; p < NTAP; ++p) {
    // stage A tap p: A[px][ci] = an[b, h+ky-1, px+kx-1, ci] (zero-pad)
    {
      int ky = (NTAP == 9) ? p / 3 : 1, kx = (NTAP == 9) ? p % 3 : 1;
      int y = h + ky - 1;
      int sx = spx + kx - 1;
      bool ok = ((unsigned)y < 64u) && ((unsigned)sx < 64u);
      const ushort* src = an + (((b * 64 + y) * 64 + sx) * 256) + seg * 64;
      uint4 z = {0u, 0u, 0u, 0u};
      #pragma unroll
      for (int j = 0; j < 8; ++j) {
        uint4 v = z;
        if (ok) v = *(const uint4*)(src + j * 8);
        *(uint4*)&sA[spx * 264 + seg * 64 + j * 8] = v;
      }
    }
    for (int cic = 0; cic < 8; ++cic) {
      if (t < NCO) {
        const ushort* srcB = wB + ((p * 8 + cic) * NCO + t) * 32;
        #pragma unroll
        for (int j = 0; j < 4; ++j)
          *(uint4*)&sB[t * 40 + j * 8] = *(const uint4*)(srcB + j * 8);
      }
      __syncthreads();
      const int krow = lane >> 4;
      bf16x8 af[MF], bfr[NF];
      #pragma unroll
      for (int m = 0; m < MF; ++m) {
        frag_cv cv;
        cv.u = *(const uint4*)&sA[((m0 + m) * 16 + (lane & 15)) * 264 + cic * 32 + krow * 8];
        af[m] = cv.v;
      }
      #pragma unroll
      for (int n = 0; n < NF; ++n) {
        frag_cv cv;
        cv.u = *(const uint4*)&sB[(co_w + n * 16 + (lane & 15)) * 40 + krow * 8];
        bfr[n] = cv.v;
      }
      #pragma unroll
      for (int m = 0; m < MF; ++m)
        #pragma unroll
        for (int n = 0; n < NF; ++n)
          acc[m][n] = __builtin_amdgcn_mfma_f32_16x16x32_bf16(af[m], bfr[n], acc[m][n], 0, 0, 0);
      __syncthreads();
    }
  }
  const int row0 = (b * 64 + h) * 64;
  if (MODE == 0) {
    #pragma unroll
    for (int m = 0; m < MF; ++m) {
      int pxo = (m0 + m) * 16 + (lane >> 4) * 4;
      #pragma unroll
      for (int n = 0; n < NF; ++n) {
        int co = co_w + n * 16 + (lane & 15);
        #pragma unroll
        for (int r = 0; r < 4; ++r)
          out[(row0 + pxo + r) * 256 + co] = acc[m][n][r];
      }
    }
  } else {
    int pxo = m0 * 16 + (lane >> 4) * 4;
    #pragma unroll
    for (int n = 0; n < NF; ++n) {
      int co = n * 16 + (lane & 15);
      #pragma unroll
      for (int r = 0; r < 4; ++r) {
        float v = acc[0][n][r];
        float o;
        if (co < 18) o = v + boff[co];
        else if (co < 27) { float mm = v + bmod[co - 18]; o = 2.f / (1.f + __expf(-mm)); }
        else o = 0.f;
        out[(row0 + pxo + r) * 32 + co] = o;
      }
    }
  }
}

// ---------------- modulated deformable conv: bilinear-gather A-tile + bf16 MFMA ----------------
__global__ __launch_bounds__(256) void k_deform(const ushort* __restrict__ an,
                                                const float* __restrict__ om,
                                                const ushort* __restrict__ wB,
                                                float* __restrict__ out) {
  __shared__ __align__(16) ushort sA[64 * 264];
  __shared__ __align__(16) ushort sB[256 * 40];
  __shared__ __align__(16) float4 sW4[9 * 64];
  __shared__ uchar2 sYX[9 * 64];
  const int h = blockIdx.x, b = blockIdx.y, t = threadIdx.x;
  const int lane = t & 63, wv = t >> 6;
  // per-(tap,pixel) bilinear specs
  for (int s = t; s < 576; s += 256) {
    int px = s & 63, p = s >> 6;
    int row = (b * 64 + h) * 64 + px;
    float dy = om[row * 32 + 2 * p];
    float dx = om[row * 32 + 2 * p + 1];
    float mk = om[row * 32 + 18 + p];
    float py = (float)(h + p / 3 - 1) + dy;
    float pxx = (float)(px + p % 3 - 1) + dx;
    float fy = floorf(py), fx = floorf(pxx);
    float ly = py - fy, lx = pxx - fx;
    int y0 = (int)fy, x0 = (int)fx;
    bool vy0 = ((unsigned)y0 < 64u), vy1 = ((unsigned)(y0 + 1) < 64u);
    bool vx0 = ((unsigned)x0 < 64u), vx1 = ((unsigned)(x0 + 1) < 64u);
    float4 wvv;
    wvv.x = (1.f - ly) * (1.f - lx) * mk * ((vy0 && vx0) ? 1.f : 0.f);
    wvv.y = (1.f - ly) * lx * mk * ((vy0 && vx1) ? 1.f : 0.f);
    wvv.z = ly * (1.f - lx) * mk * ((vy1 && vx0) ? 1.f : 0.f);
    wvv.w = ly * lx * mk * ((vy1 && vx1) ? 1.f : 0.f);
    sW4[p * 64 + px] = wvv;
    int yc = min(max(y0, -4), 250), xc = min(max(x0, -4), 250);
    sYX[p * 64 + px] = make_uchar2((unsigned char)(yc + 4), (unsigned char)(xc + 4));
  }
  __syncthreads();
  f32x4 acc[4][4];
  #pragma unroll
  for (int m = 0; m < 4; ++m)
    #pragma unroll
    for (int n = 0; n < 4; ++n) acc[m][n] = (f32x4){0.f, 0.f, 0.f, 0.f};

  const int spx = t & 63, seg = t >> 6;
  const ushort* base = an + (b * PLANE) * 256;
  for (int p = 0; p < 9; ++p) {
    // sample A_p[px][ci] for 256 ci, write bf16 to LDS
    {
      float4 wvv = sW4[p * 64 + spx];
      uchar2 yx = sYX[p * 64 + spx];
      int y0 = (int)yx.x - 4, x0 = (int)yx.y - 4;
      int y0c = min(max(y0, 0), 63), y1c = min(max(y0 + 1, 0), 63);
      int x0c = min(max(x0, 0), 63), x1c = min(max(x0 + 1, 0), 63);
      const ushort* r00 = base + (y0c * 64 + x0c) * 256 + seg * 64;
      const ushort* r01 = base + (y0c * 64 + x1c) * 256 + seg * 64;
      const ushort* r10 = base + (y1c * 64 + x0c) * 256 + seg * 64;
      const ushort* r11 = base + (y1c * 64 + x1c) * 256 + seg * 64;
      #pragma unroll
      for (int j = 0; j < 8; ++j) {
        uint4 c00 = *(const uint4*)(r00 + j * 8);
        uint4 c01 = *(const uint4*)(r01 + j * 8);
        uint4 c10 = *(const uint4*)(r10 + j * 8);
        uint4 c11 = *(const uint4*)(r11 + j * 8);
        uint ou[4];
        #pragma unroll
        for (int q = 0; q < 4; ++q) {
          uint a0 = ((const uint*)&c00)[q], a1 = ((const uint*)&c01)[q];
          uint a2 = ((const uint*)&c10)[q], a3 = ((const uint*)&c11)[q];
          float lo = wvv.x * __uint_as_float(a0 << 16) + wvv.y * __uint_as_float(a1 << 16)
                   + wvv.z * __uint_as_float(a2 << 16) + wvv.w * __uint_as_float(a3 << 16);
          float hi = wvv.x * __uint_as_float(a0 & 0xffff0000u) + wvv.y * __uint_as_float(a1 & 0xffff0000u)
                   + wvv.z * __uint_as_float(a2 & 0xffff0000u) + wvv.w * __uint_as_float(a3 & 0xffff0000u);
          ou[q] = (uint)f2bf(lo) | ((uint)f2bf(hi) << 16);
        }
        *(uint4*)&sA[spx * 264 + seg * 64 + j * 8] = *(uint4*)ou;
      }
    }
    for (int cic = 0; cic < 8; ++cic) {
      {
        const ushort* srcB = wB + ((p * 8 + cic) * 256 + t) * 32;
        #pragma unroll
        for (int j = 0; j < 4; ++j)
          *(uint4*)&sB[t * 40 + j * 8] = *(const uint4*)(srcB + j * 8);
      }
      __syncthreads();
      const int krow = lane >> 4;
      bf16x8 af[4], bfr[4];
      #pragma unroll
      for (int m = 0; m < 4; ++m) {
        frag_cv cv;
        cv.u = *(const uint4*)&sA[(m * 16 + (lane & 15)) * 264 + cic * 32 + krow * 8];
        af[m] = cv.v;
      }
      #pragma unroll
      for (int n = 0; n < 4; ++n) {
        frag_cv cv;
        cv.u = *(const uint4*)&sB[(wv * 64 + n * 16 + (lane & 15)) * 40 + krow * 8];
        bfr[n] = cv.v;
      }
      #pragma unroll
      for (int m = 0; m < 4; ++m)
        #pragma unroll
        for (int n = 0; n < 4; ++n)
          acc[m][n] = __builtin_amdgcn_mfma_f32_16x16x32_bf16(af[m], bfr[n], acc[m][n], 0, 0, 0);
      __syncthreads();
    }
  }
  const int row0 = (b * 64 + h) * 64;
  #pragma unroll
  for (int m = 0; m < 4; ++m) {
    int pxo = m * 16 + (lane >> 4) * 4;
    #pragma unroll
    for (int n = 0; n < 4; ++n) {
      int co = wv * 64 + n * 16 + (lane & 15);
      #pragma unroll
      for (int r = 0; r < 4; ++r)
        out[(row0 + pxo + r) * 256 + co] = acc[m][n][r];
    }
  }
}

// ---------------- BN stats (two-stage, deterministic) ----------------
__global__ __launch_bounds__(256) void k_statA(const float* __restrict__ t, float* __restrict__ part) {
  const int c = threadIdx.x;
  const int base = blockIdx.x * 128;
  float s1 = 0.f, s2 = 0.f;
  for (int r = 0; r < 128; ++r) {
    float v = t[(base + r) * 256 + c];
    s1 += v; s2 += v * v;
  }
  part[blockIdx.x * 512 + c] = s1;
  part[blockIdx.x * 512 + 256 + c] = s2;
}
__global__ void k_statB(const float* __restrict__ part, const float* __restrict__ g,
                        const float* __restrict__ bt, float* __restrict__ scale,
                        float* __restrict__ shift) {
  const int c = threadIdx.x;
  float s1 = 0.f, s2 = 0.f;
  for (int r = 0; r < 256; ++r) { s1 += part[r * 512 + c]; s2 += part[r * 512 + 256 + c]; }
  const float inv = 1.f / 32768.f;
  float m = s1 * inv;
  float var = s2 * inv - m * m;
  float a = g[c] * rsqrtf(var + 1e-5f);
  scale[c] = a;
  shift[c] = bt[c] - m * a;
}

// ---------------- BN+ReLU: t1 fp32 NHWC -> out1 bf16 NHWC ----------------
__global__ void k_bnrelu(const float* __restrict__ t, const float* __restrict__ scale,
                         const float* __restrict__ shift, ushort* __restrict__ o) {
  int stride = gridDim.x * blockDim.x;
  for (int i = blockIdx.x * blockDim.x + threadIdx.x; i < 8388608 / 4; i += stride) {
    float4 v = ((const float4*)t)[i];
    int c0 = (i & 63) * 4;
    float4 s = *(const float4*)&scale[c0];
    float4 sh = *(const float4*)&shift[c0];
    float q0 = fmaxf(v.x * s.x + sh.x, 0.f);
    float q1 = fmaxf(v.y * s.y + sh.y, 0.f);
    float q2 = fmaxf(v.z * s.z + sh.z, 0.f);
    float q3 = fmaxf(v.w * s.w + sh.w, 0.f);
    uint lo = (uint)f2bf(q0) | ((uint)f2bf(q1) << 16);
    uint hi = (uint)f2bf(q2) | ((uint)f2bf(q3) << 16);
    ((uint2*)o)[i] = make_uint2(lo, hi);
  }
}

// ---------------- final: relu(bn2(t2)+bn3(res)), NHWC -> NCHW fp32 ----------------
__global__ __launch_bounds__(256) void k_final(const float* __restrict__ t2, const float* __restrict__ res,
                                               const float* __restrict__ s2p, const float* __restrict__ sh2p,
                                               const float* __restrict__ s3p, const float* __restrict__ sh3p,
                                               float* __restrict__ o) {
  __shared__ __align__(16) float sT[64 * 68];
  const int h = blockIdx.x, b = blockIdx.y, t = threadIdx.x;
  const int row0 = (b * 64 + h) * 64;
  for (int chunk = 0; chunk < 4; ++chunk) {
    const int c0 = chunk * 64;
    {
      int px = t >> 2, s4 = t & 3;
      int rbase = (row0 + px) * 256 + c0 + s4 * 16;
      #pragma unroll
      for (int j = 0; j < 4; ++j) {
        int cl = s4 * 16 + j * 4;
        float4 a = *(const float4*)&t2[rbase + j * 4];
        float4 r = *(const float4*)&res[rbase + j * 4];
        float4 sa = *(const float4*)&s2p[c0 + cl];
        float4 sha = *(const float4*)&sh2p[c0 + cl];
        float4 sb = *(const float4*)&s3p[c0 + cl];
        float4 shb = *(const float4*)&sh3p[c0 + cl];
        sT[(cl + 0) * 68 + px] = fmaxf(a.x * sa.x + sha.x + r.x * sb.x + shb.x, 0.f);
        sT[(cl + 1) * 68 + px] = fmaxf(a.y * sa.y + sha.y + r.y * sb.y + shb.y, 0.f);
        sT[(cl + 2) * 68 + px] = fmaxf(a.z * sa.z + sha.z + r.z * sb.z + shb.z, 0.f);
        sT[(cl + 3) * 68 + px] = fmaxf(a.w * sa.w + sha.w + r.w * sb.w + shb.w, 0.f);
      }
    }
    __syncthreads();
    {
      int cl = t & 63, wseg = t >> 6;
      int obase = ((b * 256 + c0 + cl) * 64 + h) * 64 + wseg * 16;
      #pragma unroll
      for (int j = 0; j < 4; ++j) {
        float4 q;
        q.x = sT[cl * 68 + wseg * 16 + j * 4 + 0];
        q.y = sT[cl * 68 + wseg * 16 + j * 4 + 1];
        q.z = sT[cl * 68 + wseg * 16 + j * 4 + 2];
        q.w = sT[cl * 68 + wseg * 16 + j * 4 + 3];
        *(float4*)&o[obase + j * 4] = q;
      }
    }
    __syncthreads();
  }
}

extern "C" void kernel_launch(void* const* d_in, const int* in_sizes, int n_in,
                              void* d_out, int out_size, void* d_ws, size_t ws_size,
                              hipStream_t stream) {
  const float* x    = (const float*)d_in[0];
  const float* w1   = (const float*)d_in[2];
  const float* g1   = (const float*)d_in[4];
  const float* bt1  = (const float*)d_in[5];
  const float* woff = (const float*)d_in[6];
  const float* boff = (const float*)d_in[7];
  const float* wmod = (const float*)d_in[8];
  const float* bmod = (const float*)d_in[9];
  const float* wd   = (const float*)d_in[10];
  const float* g2   = (const float*)d_in[12];
  const float* bt2  = (const float*)d_in[13];
  const float* wds  = (const float*)d_in[14];
  const float* g3   = (const float*)d_in[16];
  const float* bt3  = (const float*)d_in[17];

  float* ws = (float*)d_ws;
  ushort* wb1  = (ushort*)ws;                    // 589824 bf16 = 294912 f32
  ushort* wbd  = (ushort*)(ws + 294912);         // 294912 f32
  ushort* wbom = (ushort*)(ws + 589824);         // 36864 f32
  ushort* wbds = (ushort*)(ws + 626688);         // 32768 f32
  float*  SC   = ws + 659456;                    // 2048 f32
  float*  part = ws + 661504;                    // 131072 f32
  ushort* xn   = (ushort*)(ws + 792576);         // 4194304 f32
  ushort* out1 = (ushort*)(ws + 4986880);        // 4194304 f32
  float*  t1   = ws + 9181184;                   // 8388608 f32 (reused as res)
  float*  t2   = ws + 17569792;                  // 8388608 f32
  float*  om   = ws + 25958400;                  // 1048576 f32  (end: 27006976 f32 = 108 MB)
  float*  res  = t1;

  dim3 ghb(64, 8);
  k_prep<<<512, 256, 0, stream>>>(w1, wd, woff, wmod, wds, wb1, wbd, wbom, wbds);
  k_x2nhwc<<<ghb, 256, 0, stream>>>(x, xn);
  k_conv<256, 9, 0><<<ghb, 256, 0, stream>>>(xn, wb1, nullptr, nullptr, t1);
  k_statA<<<256, 256, 0, stream>>>(t1, part);
  k_statB<<<1, 256, 0, stream>>>(part, g1, bt1, SC, SC + 256);
  k_bnrelu<<<2048, 256, 0, stream>>>(t1, SC, SC + 256, out1);
  k_conv<32, 9, 1><<<ghb, 256, 0, stream>>>(out1, wbom, boff, bmod, om);
  k_deform<<<ghb, 256, 0, stream>>>(out1, om, wbd, t2);
  k_statA<<<256, 256, 0, stream>>>(t2, part);
  k_statB<<<1, 256, 0, stream>>>(part, g2, bt2, SC + 512, SC + 768);
  k_conv<256, 1, 0><<<ghb, 256, 0, stream>>>(xn, wbds, nullptr, nullptr, res);
  k_statA<<<256, 256, 0, stream>>>(res, part);
  k_statB<<<1, 256, 0, stream>>>(part, g3, bt3, SC + 1024, SC + 1280);
  k_final<<<ghb, 256, 0, stream>>>(t2, res, SC + 512, SC + 768, SC + 1024, SC + 1280, (float*)d_out);
}